// Round 4
// baseline (1170.614 us; speedup 1.0000x reference)
//
#include <hip/hip_runtime.h>
#include <hip/hip_bf16.h>
#include <stdint.h>

#define N_TOK 8192
#define DIN   1024
#define DHID  4096
#define DOUT  1024
#define NE    8

typedef __attribute__((ext_vector_type(8))) __bf16 bf16x8;
typedef __attribute__((ext_vector_type(4))) float  f32x4;
typedef __attribute__((ext_vector_type(8))) unsigned short u16x8;

// RNE float->bf16 (finite inputs)
__device__ __forceinline__ unsigned short f2bfu(float f) {
    union { float f; unsigned u; } a; a.f = f;
    unsigned r = a.u + 0x7FFF + ((a.u >> 16) & 1);
    return (unsigned short)(r >> 16);
}

__device__ __forceinline__ void gload_lds16(const void* g, void* l) {
    __builtin_amdgcn_global_load_lds(
        (__attribute__((address_space(1))) void*)(void*)g,
        (__attribute__((address_space(3))) void*)l,
        16, 0, 0);
}

// ---- 64x64 cast+transpose tile as a device function (256-thread blocks) ----
// in [R][C] f32 (expert bz) -> out [C][R] bf16. t = 64x65 f32 LDS staging.
__device__ __forceinline__ void transpose_tile(const float* __restrict__ in,
                                               unsigned short* __restrict__ out,
                                               int R, int C, int bx, int by, int bz,
                                               float (*t)[65]) {
    const size_t RC = (size_t)R * C;
    const float* ine = in + (size_t)bz * RC;
    unsigned short* oute = out + (size_t)bz * RC;
    int c0 = bx * 64, r0 = by * 64;
    int tid = threadIdx.x;
    __syncthreads();   // LDS region free (prev tile's reads / prev phase done)
    #pragma unroll
    for (int it = 0; it < 4; it++) {
        int idx = it * 256 + tid;
        int r = idx >> 4, cq = (idx & 15) * 4;
        float4 v = *(const float4*)(ine + (size_t)(r0 + r) * C + c0 + cq);
        t[r][cq] = v.x; t[r][cq + 1] = v.y; t[r][cq + 2] = v.z; t[r][cq + 3] = v.w;
    }
    __syncthreads();
    #pragma unroll
    for (int it = 0; it < 2; it++) {
        int u = it * 256 + tid;
        int c = u >> 3, g = (u & 7) * 8;
        u16x8 o;
        #pragma unroll
        for (int v = 0; v < 8; v++) o[v] = f2bfu(t[g + v][c]);
        *(u16x8*)(oute + (size_t)(c0 + c) * R + r0 + g) = o;
    }
}

// ---------------- gating + fused W1 transpose + out-zeroing ----------------
__global__ void gate_kernel(const float* __restrict__ x, const float* __restrict__ Wg,
                            const float* __restrict__ bg, int* __restrict__ counts,
                            int* __restrict__ tok_list, int* __restrict__ slot_list,
                            float* __restrict__ wslot, unsigned short* __restrict__ xb,
                            const float* __restrict__ W1, unsigned short* __restrict__ w1t,
                            float* __restrict__ out_zero) {
    __shared__ float tg[64][65];
    int wv = threadIdx.x >> 6, lane = threadIdx.x & 63;
    int n = blockIdx.x * 4 + wv;
    float acc[NE];
    #pragma unroll
    for (int e = 0; e < NE; e++) acc[e] = 0.f;
    const float* xr = x + (size_t)n * DIN;
    unsigned short* xbr = xb + (size_t)n * DIN;
    #pragma unroll
    for (int i = 0; i < DIN / 256; i++) {
        int d = i * 256 + lane * 4;
        float4 xv = *(const float4*)(xr + d);
        ushort4 o;
        o.x = f2bfu(xv.x); o.y = f2bfu(xv.y); o.z = f2bfu(xv.z); o.w = f2bfu(xv.w);
        *(ushort4*)(xbr + d) = o;
        const float* w = Wg + (size_t)d * NE;
        #pragma unroll
        for (int u = 0; u < 4; u++) {
            float xs = (&xv.x)[u];
            float4 w0 = *(const float4*)(w + u * NE);
            float4 w1 = *(const float4*)(w + u * NE + 4);
            acc[0] += xs * w0.x; acc[1] += xs * w0.y; acc[2] += xs * w0.z; acc[3] += xs * w0.w;
            acc[4] += xs * w1.x; acc[5] += xs * w1.y; acc[6] += xs * w1.z; acc[7] += xs * w1.w;
        }
    }
    #pragma unroll
    for (int off = 32; off; off >>= 1)
        #pragma unroll
        for (int e = 0; e < NE; e++) acc[e] += __shfl_down(acc[e], off);
    if (lane == 0) {
        float s[NE], p[NE];
        float mx = -1e30f;
        #pragma unroll
        for (int e = 0; e < NE; e++) { s[e] = acc[e] + bg[e]; mx = fmaxf(mx, s[e]); }
        float sum = 0.f;
        #pragma unroll
        for (int e = 0; e < NE; e++) { p[e] = expf(s[e] - mx); sum += p[e]; }
        float inv = 1.f / sum;
        int e0 = 0;
        #pragma unroll
        for (int e = 1; e < NE; e++) if (s[e] > s[e0]) e0 = e;
        int e1 = (e0 == 0) ? 1 : 0;
        #pragma unroll
        for (int e = 0; e < NE; e++) if (e != e0 && s[e] > s[e1]) e1 = e;
        float p0 = p[e0] * inv, p1 = p[e1] * inv;
        float rn = 1.f / (p0 + p1 + 1e-8f);
        int pos0 = atomicAdd(&counts[e0], 1);
        tok_list[e0 * N_TOK + pos0] = n; slot_list[e0 * N_TOK + pos0] = 2 * n;     wslot[e0 * N_TOK + pos0] = p0 * rn;
        int pos1 = atomicAdd(&counts[e1], 1);
        tok_list[e1 * N_TOK + pos1] = n; slot_list[e1 * N_TOK + pos1] = 2 * n + 1; wslot[e1 * N_TOK + pos1] = p1 * rn;
    }
    // zero the output accumulator (replaces the 33MB hipMemsetAsync node); out
    // is consumed by GEMM2 which launches after GEMM1 -> ordering satisfied.
    {
        float4 z = {0.f, 0.f, 0.f, 0.f};
        float* ob = out_zero + ((size_t)blockIdx.x * 256 + threadIdx.x) * 16;
        #pragma unroll
        for (int j = 0; j < 4; j++) *(float4*)(ob + j * 4) = z;
    }
    // fused W1 transpose: tiles laid out as grid (DHID/64=64, DIN/64=16, NE)
    #pragma unroll 1
    for (int j = 0; j < 4; j++) {
        int id = blockIdx.x * 4 + j;
        int bx = id & 63, by = (id >> 6) & 15, bz = id >> 10;
        transpose_tile(W1, w1t, DIN, DHID, bx, by, bz, tg);
    }
}

// ---------------- persistent grouped gather-GEMM, 128x128 tile, BK=64, bf16 MFMA ----------------
// R2-proven K-loop/sync structure (stage -> sync(vmcnt0) -> 2x[ds_read + 16 MFMA] -> sync),
// 4 blocks/CU (the latency-hiding sweet spot — R1/R3 showed deeper/fatter schedules regress).
// NEW (R4): work issue via per-expert device atomic cursors with XCD-affinity-first stealing:
//   - balance becomes +-1 item globally (kills the +25% ragged-expert tail at static binding);
//   - pops are sequential, so an XCD's ~128 blocks work a contiguous item window; with
//     tile_n-slowest decode that window spans ~8 B-panels = 2MB -> B stays L2-hot
//     (vs 32 live panels = 8MB > 4MB L2 before).
// GEMM1 epilogue: proven scatter 2B stores. GEMM2: SPLITK=2, f32 atomicAdd merge.
template <int KDIM, int NDIM, bool IS_GEMM1, int SPLITK>
__global__ __launch_bounds__(256, 4)
void moe_gemm(const unsigned short* __restrict__ Asrc, const unsigned short* __restrict__ Bt,
              const float* __restrict__ bias, unsigned short* __restrict__ Hdst,
              float* __restrict__ Odst, const int* __restrict__ counts,
              const int* __restrict__ tok_list, const int* __restrict__ slot_list,
              const float* __restrict__ wslot, int* __restrict__ cursor,
              const float* __restrict__ W2src, unsigned short* __restrict__ w2t_dst) {
    constexpr int NT_N = NDIM / 128;
    constexpr int KLEN = KDIM / SPLITK;

    int e_own = blockIdx.x & 7;           // preferred expert == this block's XCD

    __shared__ __align__(16) unsigned short pool[2 * 128 * 64];  // As | Bs (32 KB)
    unsigned short* As = pool;
    unsigned short* Bs = pool + 128 * 64;
    __shared__ int rowid_s[128];
    __shared__ int outid_s[128];
    __shared__ float w_s[128];
    __shared__ int meta_s[5];             // e, tile_n, kh, tile_m, count

    int tid = threadIdx.x;
    int lane = tid & 63;
    int wv = tid >> 6;
    int ric = lane >> 3;
    int k8  = (lane & 7) ^ ric;
    int wm = (wv >> 1) * 64, wn = (wv & 1) * 64;
    int r16 = lane & 15, quad = lane >> 4;

    bool tdone = !IS_GEMM1;
    unsigned dmask = 0;                   // tid0-private: exhausted experts

    for (;;) {
        __syncthreads();   // prior item's epilogue reads of outid_s/w_s + LDS reuse done
        if (tid == 0) {
            int sel_e = -1, sel_idx = 0;
            #pragma unroll 1
            for (int t = 0; t < 8 && sel_e < 0; t++) {
                int ee = (e_own + t) & 7;
                if (dmask & (1u << ee)) continue;
                int p = atomicAdd(&cursor[ee], 1);
                int cnte = counts[ee];
                int Mte = (cnte + 127) >> 7;
                if (p < Mte * NT_N * SPLITK) { sel_e = ee; sel_idx = p; }
                else dmask |= (1u << ee);
            }
            if (sel_e < 0) meta_s[0] = -1;
            else {
                int cnte = counts[sel_e];
                int Mte = (cnte + 127) >> 7;
                int MS = Mte * SPLITK;
                int tn = sel_idx / MS;           // tile_n slowest -> panel window stays hot
                int rem = sel_idx - tn * MS;
                int tm = rem % Mte;              // tile_m fastest -> A slices stream
                int kh = rem / Mte;
                meta_s[0] = sel_e; meta_s[1] = tn; meta_s[2] = kh; meta_s[3] = tm; meta_s[4] = cnte;
            }
        }
        __syncthreads();
        int e = meta_s[0];
        if (e < 0) break;
        int tile_n = meta_s[1], kh = meta_s[2], tile_m = meta_s[3], count = meta_s[4];

        if (tid < 128) {
            int rr = tile_m * 128 + tid;
            if (rr >= count) rr = tile_m * 128;
            int base = e * N_TOK + rr;
            if (IS_GEMM1) { rowid_s[tid] = tok_list[base]; outid_s[tid] = slot_list[base]; }
            else          { rowid_s[tid] = slot_list[base]; outid_s[tid] = tok_list[base]; w_s[tid] = wslot[base]; }
        }
        __syncthreads();

        const int k0 = kh * KLEN;
        const unsigned short* aptr[4];
        const unsigned short* bptr[4];
        #pragma unroll
        for (int i = 0; i < 4; i++) {
            int c = wv * 4 + i;
            int row = c * 8 + ric;
            aptr[i] = Asrc + (size_t)rowid_s[row] * KDIM + k0 + k8 * 8;
            bptr[i] = Bt + ((size_t)e * NDIM + tile_n * 128 + row) * KDIM + k0 + k8 * 8;
        }

        f32x4 acc[4][4];
        #pragma unroll
        for (int i = 0; i < 4; i++)
            #pragma unroll
            for (int j = 0; j < 4; j++) acc[i][j] = (f32x4){0.f, 0.f, 0.f, 0.f};

        for (int kk = 0; kk < KLEN / 64; kk++) {
            #pragma unroll
            for (int i = 0; i < 4; i++) {
                gload_lds16(aptr[i] + kk * 64, (void*)(As + (wv * 4 + i) * 512));
                gload_lds16(bptr[i] + kk * 64, (void*)(Bs + (wv * 4 + i) * 512));
            }
            __syncthreads();
            #pragma unroll
            for (int kh2 = 0; kh2 < 2; kh2++) {
                int swk = ((kh2 * 4 + quad) ^ (r16 & 7)) * 8;   // un-swizzle at read time
                bf16x8 av[4], bv[4];
                #pragma unroll
                for (int i = 0; i < 4; i++)
                    av[i] = *(const bf16x8*)(As + (wm + i * 16 + r16) * 64 + swk);
                #pragma unroll
                for (int j = 0; j < 4; j++)
                    bv[j] = *(const bf16x8*)(Bs + (wn + j * 16 + r16) * 64 + swk);
                #pragma unroll
                for (int i = 0; i < 4; i++)
                    #pragma unroll
                    for (int j = 0; j < 4; j++)
                        acc[i][j] = __builtin_amdgcn_mfma_f32_16x16x32_bf16(av[i], bv[j], acc[i][j], 0, 0, 0);
            }
            __syncthreads();
        }

        // epilogue: D row = quad*4+reg, col = lane&15 within each 16x16 tile
        float bias_r[4];
        #pragma unroll
        for (int j = 0; j < 4; j++)
            bias_r[j] = bias[(size_t)e * NDIM + tile_n * 128 + wn + j * 16 + r16];
        #pragma unroll
        for (int i = 0; i < 4; i++) {
            #pragma unroll
            for (int reg = 0; reg < 4; reg++) {
                int rr = wm + i * 16 + quad * 4 + reg;
                if (tile_m * 128 + rr >= count) continue;
                #pragma unroll
                for (int j = 0; j < 4; j++) {
                    int col = tile_n * 128 + wn + j * 16 + r16;
                    float v = acc[i][j][reg];
                    if (IS_GEMM1) {
                        v = fmaxf(v + bias_r[j], 0.f);
                        Hdst[(size_t)outid_s[rr] * NDIM + col] = f2bfu(v);
                    } else {
                        if (kh == 0) v += bias_r[j];
                        atomicAdd(&Odst[(size_t)outid_s[rr] * NDIM + col], w_s[rr] * v);
                    }
                }
            }
        }

        // fused W2 transpose after the first item (overlaps other blocks' compute)
        if constexpr (IS_GEMM1) {
            if (!tdone) {
                tdone = true;
                float (*t)[65] = (float(*)[65])pool;   // 16.7 KB <= 32 KB pool, As/Bs dead here
                #pragma unroll 1
                for (int j = 0; j < 8; j++) {
                    int id = blockIdx.x * 8 + j;       // tiles: grid (DOUT/64=16, DHID/64=64, NE)
                    int bx = id & 15, by = (id >> 4) & 63, bz = id >> 10;
                    transpose_tile(W2src, w2t_dst, DHID, DOUT, bx, by, bz, t);
                }
            }
        }
    }

    // blocks that never got an item still owe their transpose chunk
    if constexpr (IS_GEMM1) {
        if (!tdone) {
            float (*t)[65] = (float(*)[65])pool;
            #pragma unroll 1
            for (int j = 0; j < 8; j++) {
                int id = blockIdx.x * 8 + j;
                int bx = id & 15, by = (id >> 4) & 63, bz = id >> 10;
                transpose_tile(W2src, w2t_dst, DHID, DOUT, bx, by, bz, t);
            }
        }
    }
}

extern "C" void kernel_launch(void* const* d_in, const int* in_sizes, int n_in,
                              void* d_out, int out_size, void* d_ws, size_t ws_size,
                              hipStream_t stream) {
    const float* x  = (const float*)d_in[0];
    const float* W1 = (const float*)d_in[1];
    const float* b1 = (const float*)d_in[2];
    const float* W2 = (const float*)d_in[3];
    const float* b2 = (const float*)d_in[4];
    const float* Wg = (const float*)d_in[5];
    const float* bg = (const float*)d_in[6];
    float* out = (float*)d_out;

    char* ws = (char*)d_ws;
    unsigned short* xb  = (unsigned short*)(ws + 0);            // 16 MB
    unsigned short* w1t = (unsigned short*)(ws + 16777216);     // 64 MB  [E][DHID][DIN]
    unsigned short* w2t = (unsigned short*)(ws + 83886080);     // 64 MB  [E][DOUT][DHID]
    unsigned short* h   = (unsigned short*)(ws + 150994944);    // 128 MB [2N][DHID]
    int*   counts    = (int*)(ws + 285212672);                  // 256B region: counts|cur1|cur2
    int*   cur1      = counts + 8;
    int*   cur2      = counts + 16;
    int*   tok_list  = (int*)(ws + 285212928);
    int*   slot_list = (int*)(ws + 285475072);
    float* wslot     = (float*)(ws + 285737216);

    hipMemsetAsync(counts, 0, 256, stream);   // zeroes counts + both cursor arrays

    gate_kernel<<<N_TOK / 4, 256, 0, stream>>>(x, Wg, bg, counts, tok_list, slot_list, wslot, xb,
                                               W1, w1t, out);

    moe_gemm<DIN, DHID, true, 1><<<1024, 256, 0, stream>>>(
        xb, w1t, b1, h, nullptr, counts, tok_list, slot_list, wslot, cur1, W2, w2t);
    moe_gemm<DHID, DOUT, false, 2><<<1024, 256, 0, stream>>>(
        h, w2t, b2, nullptr, out, counts, tok_list, slot_list, wslot, cur2, nullptr, nullptr);
}